// Round 12
// baseline (1089.700 us; speedup 1.0000x reference)
//
#include <hip/hip_runtime.h>
#include <hip/hip_bf16.h>
#include <cstddef>

// MCSHeteroGNN: 2-layer hetero GAT, CSR-gather, register-resident transforms,
// merged 3-type dst kernel: shfl-dedup'd attention weights, scalarized
// rp/cols loads (readfirstlane -> s_load), dual-side interleaved gathers.
// Node types: idle(100k), quasi(100k), task(50k). 5 edge types x 500k edges.
//
// ws layout (bytes), total ~118.5 MB:
//   flag    @ 0
//   params  @ 256         (f32 widened params; feature slots unused)
//   h  bf16 @ 7,600,000   (32,000,000) [idle|quasi|task]
//   hs bf16 @ 39,600,000  (57,600,000) [450k x 64]
//   als f32 @ 97,200,000  ( 7,200,000) [450k x 4]
//   rowptr  @104,400,000  (5 x 400,032)
//   cursor  @106,400,320  (5 x 400,032)
//   cols    @108,400,480  (5 x 2,000,000)
//   part    @118,400,480  (5 x 2,048)

static constexpr int NI = 100000, NQ = 100000, NT = 50000, NE = 500000;

__device__ __forceinline__ float b2f(__hip_bfloat16 x) { return __bfloat162float(x); }
__device__ __forceinline__ __hip_bfloat16 f2b(float x) { return __float2bfloat16(x); }
__device__ __forceinline__ int rfl(int v) { return __builtin_amdgcn_readfirstlane(v); }

__global__ void k_detect(const unsigned short* __restrict__ x, int* __restrict__ flag)
{
    __shared__ int sh[256];
    int tid = threadIdx.x;
    int sane = 0;
    for (int i = tid * 2; i < 2048; i += 512) {
        unsigned short h = x[i];
        int e = (h >> 7) & 0xFF;
        if (h == 0 || (e >= 100 && e <= 140)) sane++;
    }
    sh[tid] = sane;
    __syncthreads();
    for (int s = 128; s; s >>= 1) { if (tid < s) sh[tid] += sh[tid + s]; __syncthreads(); }
    if (tid == 0) *flag = (sh[0] < 512) ? 1 : 0;   // 1 = buffers are f32
}

struct ConvArgs { const void* src[16]; float* dst[16]; int n[16]; };

__global__ void k_convert(ConvArgs a, const int* __restrict__ flag)
{
    int t = blockIdx.y;
    int i = blockIdx.x * 256 + threadIdx.x;
    if (i >= a.n[t]) return;
    float v = (*flag) ? ((const float*)a.src[t])[i]
                      : b2f(((const __hip_bfloat16*)a.src[t])[i]);
    a.dst[t][i] = v;
}

// ------------- input projection: h = relu(x @ W + b), dual-dtype -----------
__global__ void k_inproj(const void* __restrict__ xv, int N, int F,
                         const float* __restrict__ W, const float* __restrict__ b,
                         __hip_bfloat16* __restrict__ h, const int* __restrict__ flag)
{
    __shared__ float Wsh[8 * 64];
    __shared__ float bsh[64];
    int tid = threadIdx.x;
    for (int i = tid; i < F * 64; i += 256) Wsh[i] = W[i];
    if (tid < 64) bsh[tid] = b[tid];
    __syncthreads();
    int col = tid & 63;
    int n = blockIdx.x * 4 + (tid >> 6);
    if (n >= N) return;
    float acc = bsh[col];
    if (*flag) {
        const float* xr = (const float*)xv + (size_t)n * F;
        for (int k = 0; k < F; ++k) acc += xr[k] * Wsh[k * 64 + col];
    } else {
        const __hip_bfloat16* xr = (const __hip_bfloat16*)xv + (size_t)n * F;
        for (int k = 0; k < F; ++k) acc += b2f(xr[k]) * Wsh[k * 64 + col];
    }
    h[(size_t)n * 64 + col] = f2b(fmaxf(acc, 0.f));
}

// ---- all 5 etypes' hs = h_src @ Wsrc + als; W in VGPRs, h via readlane ----
struct TfArgs {
    const __hip_bfloat16* hsrc[5];
    const float* W[5];
    const float* avec[5];
    __hip_bfloat16* hs[5];
    float* als[5];
};
__global__ void __launch_bounds__(256) k_transform_all(TfArgs a)
{
    int tid = threadIdx.x;
    int c = tid & 63, wid = tid >> 6;
    int base = blockIdx.x * 80;               // 80 rows/block; 80 | 100000
    int j = base / 100000;
    const float* W = a.W[j];
    float wreg[64];
#pragma unroll
    for (int k = 0; k < 64; ++k) wreg[k] = W[k * 64 + c];
    float ac = a.avec[j][c];
    int nl0 = base - j * 100000 + wid * 20;
    const __hip_bfloat16* hsrc = a.hsrc[j];
    __hip_bfloat16* hs = a.hs[j];
    float* als = a.als[j];
    for (int r = 0; r < 20; ++r) {
        int nl = nl0 + r;
        float hv = b2f(hsrc[(size_t)nl * 64 + c]);
        int hb = __float_as_int(hv);
        float a0 = 0.f, a1 = 0.f, a2 = 0.f, a3 = 0.f;
#pragma unroll
        for (int k = 0; k < 64; k += 4) {
            float h0 = __int_as_float(__builtin_amdgcn_readlane(hb, k));
            float h1 = __int_as_float(__builtin_amdgcn_readlane(hb, k + 1));
            float h2 = __int_as_float(__builtin_amdgcn_readlane(hb, k + 2));
            float h3 = __int_as_float(__builtin_amdgcn_readlane(hb, k + 3));
            a0 = fmaf(h0, wreg[k], a0);
            a1 = fmaf(h1, wreg[k + 1], a1);
            a2 = fmaf(h2, wreg[k + 2], a2);
            a3 = fmaf(h3, wreg[k + 3], a3);
        }
        float acc = (a0 + a1) + (a2 + a3);
        hs[(size_t)nl * 64 + c] = f2b(acc);
        float p = acc * ac;
        p += __shfl_xor(p, 8, 16);
        p += __shfl_xor(p, 4, 16);
        p += __shfl_xor(p, 2, 16);
        p += __shfl_xor(p, 1, 16);
        if ((c & 15) == 0) als[(size_t)nl * 4 + (c >> 4)] = p;
    }
}

// ------------------- batched counting sort by dst (5 etypes) ---------------
struct SortArgs {
    const int* ei[5]; int* rowptr[5]; int* cursor[5]; int* cols[5]; int* part[5];
    int n[5];   // Ndst+1
};
__global__ void k_hist5(SortArgs s)
{
    int j = blockIdx.y;
    int e = blockIdx.x * 256 + threadIdx.x;
    if (e >= NE) return;
    atomicAdd(&s.rowptr[j][s.ei[j][NE + e] + 1], 1);
}
__global__ void k_scanb5(SortArgs s)
{
    __shared__ int sh[256];
    int j = blockIdx.y;
    int* a = s.rowptr[j];
    int n = s.n[j];
    int tid = threadIdx.x;
    int i = blockIdx.x * 256 + tid;
    int v = (i < n) ? a[i] : 0;
    sh[tid] = v; __syncthreads();
    for (int off = 1; off < 256; off <<= 1) {
        int t = (tid >= off) ? sh[tid - off] : 0;
        __syncthreads();
        sh[tid] += t;
        __syncthreads();
    }
    if (i < n) a[i] = sh[tid];
    if (tid == 255) s.part[j][blockIdx.x] = sh[255];
}
__global__ void k_scanp5(SortArgs s)
{
    __shared__ int sh[512];
    int j = blockIdx.x;
    int* part = s.part[j];
    int tid = threadIdx.x;
    int v = (tid < 391) ? part[tid] : 0;
    sh[tid] = v; __syncthreads();
    for (int off = 1; off < 512; off <<= 1) {
        int t = (tid >= off) ? sh[tid - off] : 0;
        __syncthreads();
        sh[tid] += t;
        __syncthreads();
    }
    if (tid < 391) part[tid] = sh[tid] - v;    // exclusive
}
__global__ void k_scana5(SortArgs s)
{
    int j = blockIdx.y;
    int i = blockIdx.x * 256 + threadIdx.x;
    if (i < s.n[j]) s.rowptr[j][i] += s.part[j][blockIdx.x];
}
__global__ void k_scatter5(SortArgs s)
{
    int j = blockIdx.y;
    int e = blockIdx.x * 256 + threadIdx.x;
    if (e >= NE) return;
    const int* ei = s.ei[j];
    int src = ei[e], d = ei[NE + e];
    int pos = atomicAdd(&s.cursor[j][d], 1);
    s.cols[j][pos] = src;
}

// ------------------ fused per-dst GAT gather + LN + ReLU -------------------
// - w-dedup: lanes 0..31 compute w for (slot u, head) once; others shfl it.
// - rp/cols indices made wave-uniform via readfirstlane -> scalar loads.
// - dual-side interleave: both etypes' gathers issued before consumption.
__device__ __forceinline__ void gat_dual(int n, int lane, int c, int hh, float hrow,
    const float* We0, const float* We1,
    const int* __restrict__ rp0, const int* __restrict__ cols0,
    const __hip_bfloat16* __restrict__ hs0, const float* __restrict__ als0,
    const int* __restrict__ rp1, const int* __restrict__ cols1,
    const __hip_bfloat16* __restrict__ hs1, const float* __restrict__ als1,
    float& out0, float& out1)
{
    float aldv0 = 0.f, aldv1 = 0.f;
#pragma unroll
    for (int hp = 0; hp < 4; ++hp) {
        float v0 = hrow * We0[c * 4 + hp];
        float v1 = hrow * We1[c * 4 + hp];
#pragma unroll
        for (int m = 32; m >= 1; m >>= 1) {
            v0 += __shfl_xor(v0, m, 64);
            v1 += __shfl_xor(v1, m, 64);
        }
        if (hh == hp) { aldv0 = v0; aldv1 = v1; }
    }
    float aldc0 = __shfl(aldv0, (lane & 3) * 16, 64);
    float aldc1 = __shfl(aldv1, (lane & 3) * 16, 64);
    int us = (lane >> 2) & 7;
    int beg0 = rfl(rp0[n]), end0 = rfl(rp0[n + 1]);
    int beg1 = rfl(rp1[n]), end1 = rfl(rp1[n + 1]);
    float acc0 = 0.f, den0 = 0.f, acc1 = 0.f, den1 = 0.f;
    int e0 = beg0, e1 = beg1;
    while (e0 < end0 || e1 < end1) {
        bool a0 = e0 < end0, a1 = e1 < end1;
        int i0[8], i1[8];
        if (a0) {
#pragma unroll
            for (int u = 0; u < 8; ++u) {
                int ee = e0 + u;
                i0[u] = cols0[ee < end0 ? ee : beg0];
            }
        }
        if (a1) {
#pragma unroll
            for (int u = 0; u < 8; ++u) {
                int ee = e1 + u;
                i1[u] = cols1[ee < end1 ? ee : beg1];
            }
        }
        float w0c = 0.f, w1c = 0.f;
        if (a0) {
            float alv = als0[(size_t)i0[us] * 4 + (lane & 3)] + aldc0;
            alv = (alv > 0.f) ? alv : 0.2f * alv;
            w0c = __expf(fminf(alv, 60.f));
            if (e0 + us >= end0) w0c = 0.f;
        }
        if (a1) {
            float alv = als1[(size_t)i1[us] * 4 + (lane & 3)] + aldc1;
            alv = (alv > 0.f) ? alv : 0.2f * alv;
            w1c = __expf(fminf(alv, 60.f));
            if (e1 + us >= end1) w1c = 0.f;
        }
        float g0[8], g1[8];
        if (a0) {
#pragma unroll
            for (int u = 0; u < 8; ++u) g0[u] = b2f(hs0[(size_t)i0[u] * 64 + c]);
        }
        if (a1) {
#pragma unroll
            for (int u = 0; u < 8; ++u) g1[u] = b2f(hs1[(size_t)i1[u] * 64 + c]);
        }
        if (a0) {
#pragma unroll
            for (int u = 0; u < 8; ++u) {
                float w = __shfl(w0c, u * 4 + hh, 64);
                acc0 = fmaf(w, g0[u], acc0);
                den0 += w;
            }
        }
        if (a1) {
#pragma unroll
            for (int u = 0; u < 8; ++u) {
                float w = __shfl(w1c, u * 4 + hh, 64);
                acc1 = fmaf(w, g1[u], acc1);
                den1 += w;
            }
        }
        e0 += 8; e1 += 8;
    }
    out0 = acc0 / (den0 + 1e-16f);
    out1 = acc1 / (den1 + 1e-16f);
}

__device__ __forceinline__ float gat_single(int n, int lane, int c, int hh, float hrow,
    const float* We, const int* __restrict__ rp, const int* __restrict__ cols,
    const __hip_bfloat16* __restrict__ hs, const float* __restrict__ als)
{
    float aldv = 0.f;
#pragma unroll
    for (int hp = 0; hp < 4; ++hp) {
        float v = hrow * We[c * 4 + hp];
#pragma unroll
        for (int m = 32; m >= 1; m >>= 1) v += __shfl_xor(v, m, 64);
        if (hh == hp) aldv = v;
    }
    float aldc = __shfl(aldv, (lane & 3) * 16, 64);
    int us = (lane >> 2) & 7;
    int beg = rfl(rp[n]), end = rfl(rp[n + 1]);
    float acc = 0.f, den = 0.f;
    for (int e = beg; e < end; e += 8) {
        int idx[8];
#pragma unroll
        for (int u = 0; u < 8; ++u) {
            int ee = e + u;
            idx[u] = cols[ee < end ? ee : beg];
        }
        float alv = als[(size_t)idx[us] * 4 + (lane & 3)] + aldc;
        alv = (alv > 0.f) ? alv : 0.2f * alv;
        float wcomp = __expf(fminf(alv, 60.f));
        if (e + us >= end) wcomp = 0.f;
        float gv[8];
#pragma unroll
        for (int u = 0; u < 8; ++u) gv[u] = b2f(hs[(size_t)idx[u] * 64 + c]);
#pragma unroll
        for (int u = 0; u < 8; ++u) {
            float w = __shfl(wcomp, u * 4 + hh, 64);
            acc = fmaf(w, gv[u], acc);
            den += w;
        }
    }
    return acc / (den + 1e-16f);
}

struct DstArgs {
    __hip_bfloat16* h; int net; int last; int pad;
    const int* rp0; const int* cols0; const __hip_bfloat16* hs0; const float* als0;
    const float* Wd0; const float* ad0; const float* b0;
    const int* rp1; const int* cols1; const __hip_bfloat16* hs1; const float* als1;
    const float* Wd1; const float* ad1; const float* b1;
    const float* g; const float* bb;
    void* out; size_t obase; const int* flag;
};
struct DstAll { DstArgs a[3]; int blkoff[4]; };

__global__ void __launch_bounds__(256) k_dst(DstAll all)
{
    int bid = blockIdx.x;
    int t = (bid >= all.blkoff[1]) + (bid >= all.blkoff[2]);
    const DstArgs& a = all.a[t];
    __shared__ float We0[256], We1[256];
    int tid = threadIdx.x;
    {
        int k = tid >> 2, h2 = tid & 3;
        float s0 = 0.f;
        for (int cc = 0; cc < 16; ++cc)
            s0 += a.Wd0[k * 64 + h2 * 16 + cc] * a.ad0[h2 * 16 + cc];
        We0[tid] = s0;
        if (a.net > 1) {
            float s1 = 0.f;
            for (int cc = 0; cc < 16; ++cc)
                s1 += a.Wd1[k * 64 + h2 * 16 + cc] * a.ad1[h2 * 16 + cc];
            We1[tid] = s1;
        }
    }
    __syncthreads();
    int wid = tid >> 6, lane = tid & 63, c = lane, hh = c >> 4;
    float b0c = a.b0[c];
    float b1c = (a.net > 1) ? a.b1[c] : 0.f;
    float gc = a.g[c], bbc = a.bb[c];
    int base = (bid - all.blkoff[t]) * 16;    // 16 nodes/block
    for (int r = 0; r < 4; ++r) {
        int n = base + r * 4 + wid;
        size_t i64 = (size_t)n * 64 + c;
        float hrow = b2f(a.h[i64]);
        float x = hrow + b0c + b1c;
        if (a.net > 1) {
            float o0, o1;
            gat_dual(n, lane, c, hh, hrow, We0, We1,
                     a.rp0, a.cols0, a.hs0, a.als0,
                     a.rp1, a.cols1, a.hs1, a.als1, o0, o1);
            x += o0 + o1;
        } else {
            x += gat_single(n, lane, c, hh, hrow, We0, a.rp0, a.cols0, a.hs0, a.als0);
        }
        float s = x;
#pragma unroll
        for (int off = 32; off >= 1; off >>= 1) s += __shfl_xor(s, off, 64);
        float mu = s * (1.f / 64.f);
        float dlt = x - mu;
        float v2 = dlt * dlt;
#pragma unroll
        for (int off = 32; off >= 1; off >>= 1) v2 += __shfl_xor(v2, off, 64);
        float y = dlt * rsqrtf(v2 * (1.f / 64.f) + 1e-5f) * gc + bbc;
        y = fmaxf(y, 0.f);
        if (!a.last) a.h[i64] = f2b(y);
        else {
            if (*a.flag) ((float*)a.out)[a.obase + i64] = y;
            else         ((__hip_bfloat16*)a.out)[a.obase + i64] = f2b(y);
        }
    }
}

extern "C" void kernel_launch(void* const* d_in, const int* in_sizes, int n_in,
                              void* d_out, int out_size, void* d_ws, size_t ws_size,
                              hipStream_t stream)
{
    (void)n_in; (void)out_size; (void)ws_size;
    char* ws = (char*)d_ws;
    int* flag = (int*)ws;
    float* params = (float*)(ws + 256);

    size_t off[17]; off[0] = 0;
    for (int i = 0; i < 16; ++i) off[i + 1] = off[i] + (size_t)in_sizes[i];

    const float* Wi = params + off[3]; const float* bi = params + off[4];
    const float* Wq = params + off[5]; const float* bq = params + off[6];
    const float* Wt = params + off[7]; const float* bt = params + off[8];
    const float* Wsrc = params + off[9];
    const float* Wdst = params + off[10];
    const float* asrc = params + off[11];
    const float* adst = params + off[12];
    const float* cbias = params + off[13];
    const float* lng = params + off[14];
    const float* lnb = params + off[15];

    __hip_bfloat16* h   = (__hip_bfloat16*)(ws + 7600000);
    __hip_bfloat16* h_i = h;
    __hip_bfloat16* h_q = h + (size_t)NI * 64;
    __hip_bfloat16* h_t = h + (size_t)(NI + NQ) * 64;
    __hip_bfloat16* hs_all = (__hip_bfloat16*)(ws + 39600000);
    float* als_all = (float*)(ws + 97200000);
    const size_t rowbase[5] = { 0, 100000, 200000, 300000, 400000 };

    const size_t RPS = 400032;
    SortArgs sa;
    const int Ndst_of[5] = { NI, NQ, NI, NT, NQ };
    for (int j = 0; j < 5; ++j) {
        sa.ei[j]     = (const int*)d_in[16 + j];
        sa.rowptr[j] = (int*)(ws + 104400000 + j * RPS);
        sa.cursor[j] = (int*)(ws + 106400320 + j * RPS);
        sa.cols[j]   = (int*)(ws + 108400480 + (size_t)j * 2000000);
        sa.part[j]   = (int*)(ws + 118400480 + j * 2048);
        sa.n[j]      = Ndst_of[j] + 1;
    }

    // ---- dtype detect + widen PARAM tensors (3..15) only ----
    k_detect<<<1, 256, 0, stream>>>((const unsigned short*)d_in[0], flag);
    ConvArgs ca;
    for (int i = 0; i < 16; ++i) {
        ca.src[i] = d_in[i];
        ca.dst[i] = params + off[i];
        ca.n[i] = (i >= 3) ? in_sizes[i] : 0;
    }
    k_convert<<<dim3(160, 16), 256, 0, stream>>>(ca, flag);

    // ---- input projections ----
    k_inproj<<<(NI + 3) / 4, 256, 0, stream>>>(d_in[0], NI, 8, Wi, bi, h_i, flag);
    k_inproj<<<(NQ + 3) / 4, 256, 0, stream>>>(d_in[1], NQ, 6, Wq, bq, h_q, flag);
    k_inproj<<<(NT + 3) / 4, 256, 0, stream>>>(d_in[2], NT, 8, Wt, bt, h_t, flag);

    // ---- batched counting sort (reused by both layers) ----
    hipMemsetAsync(ws + 104400000, 0, 5 * RPS, stream);
    k_hist5<<<dim3((NE + 255) / 256, 5), 256, 0, stream>>>(sa);
    k_scanb5<<<dim3(391, 5), 256, 0, stream>>>(sa);
    k_scanp5<<<5, 512, 0, stream>>>(sa);
    k_scana5<<<dim3(391, 5), 256, 0, stream>>>(sa);
    hipMemcpyAsync(ws + 106400320, ws + 104400000, 5 * RPS, hipMemcpyDeviceToDevice, stream);
    k_scatter5<<<dim3((NE + 255) / 256, 5), 256, 0, stream>>>(sa);

    const __hip_bfloat16* hsrc_of[5] = { h_i, h_i, h_q, h_q, h_t };

    for (int l = 0; l < 2; ++l) {
        TfArgs ta;
        for (int j = 0; j < 5; ++j) {
            ta.hsrc[j] = hsrc_of[j];
            ta.W[j] = Wsrc + (size_t)(l * 5 + j) * 4096;
            ta.avec[j] = asrc + (l * 5 + j) * 64;
            ta.hs[j] = hs_all + rowbase[j] * 64;
            ta.als[j] = als_all + rowbase[j] * 4;
        }
        k_transform_all<<<450000 / 80, 256, 0, stream>>>(ta);

        int last = (l == 1);
        DstAll da;
        da.blkoff[0] = 0; da.blkoff[1] = NI / 16;
        da.blkoff[2] = NI / 16 + NQ / 16; da.blkoff[3] = NI / 16 + NQ / 16 + NT / 16;
        struct Spec { __hip_bfloat16* hd; int j0, j1, lnidx; size_t obase; };
        Spec sp[3] = {
            { h_i, 0, 2, 0, 0 },
            { h_q, 1, 4, 1, (size_t)NI * 64 },
            { h_t, 3, -1, 2, (size_t)(NI + NQ) * 64 },
        };
        for (int t = 0; t < 3; ++t) {
            DstArgs& dd = da.a[t];
            dd.h = sp[t].hd; dd.net = (sp[t].j1 >= 0) ? 2 : 1; dd.last = last; dd.pad = 0;
            int j0 = sp[t].j0;
            dd.rp0 = sa.rowptr[j0]; dd.cols0 = sa.cols[j0];
            dd.hs0 = hs_all + rowbase[j0] * 64; dd.als0 = als_all + rowbase[j0] * 4;
            dd.Wd0 = Wdst + (size_t)(l * 5 + j0) * 4096;
            dd.ad0 = adst + (l * 5 + j0) * 64;
            dd.b0 = cbias + (size_t)(l * 5 + j0) * 64;
            int jj = (sp[t].j1 >= 0) ? sp[t].j1 : j0;
            dd.rp1 = sa.rowptr[jj]; dd.cols1 = sa.cols[jj];
            dd.hs1 = hs_all + rowbase[jj] * 64; dd.als1 = als_all + rowbase[jj] * 4;
            dd.Wd1 = Wdst + (size_t)(l * 5 + jj) * 4096;
            dd.ad1 = adst + (l * 5 + jj) * 64;
            dd.b1 = cbias + (size_t)(l * 5 + jj) * 64;
            dd.g = lng + (size_t)(l * 3 + sp[t].lnidx) * 64;
            dd.bb = lnb + (size_t)(l * 3 + sp[t].lnidx) * 64;
            dd.out = d_out; dd.obase = sp[t].obase; dd.flag = flag;
        }
        k_dst<<<da.blkoff[3], 256, 0, stream>>>(da);
    }
}

// Round 14
// 755.306 us; speedup vs baseline: 1.4427x; 1.4427x over previous
//
#include <hip/hip_runtime.h>
#include <hip/hip_bf16.h>
#include <cstddef>

// MCSHeteroGNN: 2-layer hetero GAT, CSR-gather, register-resident transforms,
// merged 3-type dst kernel (round-11 best), two-phase LDS-binned radix sort.
// Per-etype bucket shift: task dst (50k) uses 512-wide buckets so occupancy
// stays ~5100/bucket for all 5 etypes (round-13 crash was task overflow).
//
// ws layout (bytes), total ~132.1 MB (<=137.2 proven in round 3):
//   flag    @ 0
//   params  @ 256          (f32 widened params)
//   h  bf16 @ 7,600,000    (32,000,000) [idle|quasi|task]
//   hs bf16 @ 39,600,000   (57,600,000) [450k x 64]
//   als f32 @ 97,200,000   ( 7,200,000) [450k x 4]
//   rowptr  @ 104,400,000  (5 x 400,032)
//   cols    @ 106,400,384  (5 x 2,000,000)
//   pairs   @ 116,400,384  (5 x 128 x 6144 x 4 = 15,728,640)
//   gcnt    @ 132,129,024  (5 x 128 x 4)
//   bbase   @ 132,131,584  (5 x 128 x 4)

static constexpr int NI = 100000, NQ = 100000, NT = 50000, NE = 500000;
static constexpr int NB = 128, BCAP = 6144;
__device__ __constant__ const int SHIFT_OF[5] = { 10, 10, 10, 9, 10 };

__device__ __forceinline__ float b2f(__hip_bfloat16 x) { return __bfloat162float(x); }
__device__ __forceinline__ __hip_bfloat16 f2b(float x) { return __float2bfloat16(x); }

__global__ void k_detect(const unsigned short* __restrict__ x, int* __restrict__ flag)
{
    __shared__ int sh[256];
    int tid = threadIdx.x;
    int sane = 0;
    for (int i = tid * 2; i < 2048; i += 512) {
        unsigned short h = x[i];
        int e = (h >> 7) & 0xFF;
        if (h == 0 || (e >= 100 && e <= 140)) sane++;
    }
    sh[tid] = sane;
    __syncthreads();
    for (int s = 128; s; s >>= 1) { if (tid < s) sh[tid] += sh[tid + s]; __syncthreads(); }
    if (tid == 0) *flag = (sh[0] < 512) ? 1 : 0;   // 1 = buffers are f32
}

struct ConvArgs { const void* src[16]; float* dst[16]; int n[16]; };

__global__ void k_convert(ConvArgs a, const int* __restrict__ flag)
{
    int t = blockIdx.y;
    int i = blockIdx.x * 256 + threadIdx.x;
    if (i >= a.n[t]) return;
    float v = (*flag) ? ((const float*)a.src[t])[i]
                      : b2f(((const __hip_bfloat16*)a.src[t])[i]);
    a.dst[t][i] = v;
}

// ------------- input projection: h = relu(x @ W + b), dual-dtype -----------
__global__ void k_inproj(const void* __restrict__ xv, int N, int F,
                         const float* __restrict__ W, const float* __restrict__ b,
                         __hip_bfloat16* __restrict__ h, const int* __restrict__ flag)
{
    __shared__ float Wsh[8 * 64];
    __shared__ float bsh[64];
    int tid = threadIdx.x;
    for (int i = tid; i < F * 64; i += 256) Wsh[i] = W[i];
    if (tid < 64) bsh[tid] = b[tid];
    __syncthreads();
    int col = tid & 63;
    int n = blockIdx.x * 4 + (tid >> 6);
    if (n >= N) return;
    float acc = bsh[col];
    if (*flag) {
        const float* xr = (const float*)xv + (size_t)n * F;
        for (int k = 0; k < F; ++k) acc += xr[k] * Wsh[k * 64 + col];
    } else {
        const __hip_bfloat16* xr = (const __hip_bfloat16*)xv + (size_t)n * F;
        for (int k = 0; k < F; ++k) acc += b2f(xr[k]) * Wsh[k * 64 + col];
    }
    h[(size_t)n * 64 + col] = f2b(fmaxf(acc, 0.f));
}

// ---- all 5 etypes' hs = h_src @ Wsrc + als; W in VGPRs, h via readlane ----
struct TfArgs {
    const __hip_bfloat16* hsrc[5];
    const float* W[5];
    const float* avec[5];
    __hip_bfloat16* hs[5];
    float* als[5];
};
__global__ void __launch_bounds__(256) k_transform_all(TfArgs a)
{
    int tid = threadIdx.x;
    int c = tid & 63, wid = tid >> 6;
    int base = blockIdx.x * 80;               // 80 rows/block; 80 | 100000
    int j = base / 100000;
    const float* W = a.W[j];
    float wreg[64];
#pragma unroll
    for (int k = 0; k < 64; ++k) wreg[k] = W[k * 64 + c];
    float ac = a.avec[j][c];
    int nl0 = base - j * 100000 + wid * 20;
    const __hip_bfloat16* hsrc = a.hsrc[j];
    __hip_bfloat16* hs = a.hs[j];
    float* als = a.als[j];
    for (int r = 0; r < 20; ++r) {
        int nl = nl0 + r;
        float hv = b2f(hsrc[(size_t)nl * 64 + c]);
        int hb = __float_as_int(hv);
        float a0 = 0.f, a1 = 0.f, a2 = 0.f, a3 = 0.f;
#pragma unroll
        for (int k = 0; k < 64; k += 4) {
            float h0 = __int_as_float(__builtin_amdgcn_readlane(hb, k));
            float h1 = __int_as_float(__builtin_amdgcn_readlane(hb, k + 1));
            float h2 = __int_as_float(__builtin_amdgcn_readlane(hb, k + 2));
            float h3 = __int_as_float(__builtin_amdgcn_readlane(hb, k + 3));
            a0 = fmaf(h0, wreg[k], a0);
            a1 = fmaf(h1, wreg[k + 1], a1);
            a2 = fmaf(h2, wreg[k + 2], a2);
            a3 = fmaf(h3, wreg[k + 3], a3);
        }
        float acc = (a0 + a1) + (a2 + a3);
        hs[(size_t)nl * 64 + c] = f2b(acc);
        float p = acc * ac;
        p += __shfl_xor(p, 8, 16);
        p += __shfl_xor(p, 4, 16);
        p += __shfl_xor(p, 2, 16);
        p += __shfl_xor(p, 1, 16);
        if ((c & 15) == 0) als[(size_t)nl * 4 + (c >> 4)] = p;
    }
}

// ----------------- two-phase radix sort by dst (5 etypes) ------------------
// Phase A: chunk->LDS counting sort by bucket (d>>sh); write packed
// (dlocal<<17|src) pairs as contiguous runs into per-bucket regions.
struct BinArgs { const int* ei[5]; int* pairs[5]; int* gcnt[5]; };
__global__ void __launch_bounds__(256) k_bin(BinArgs a)
{
    int j = blockIdx.y;
    int sh = SHIFT_OF[j];
    const int* ei = a.ei[j];
    __shared__ int cnts[NB], scn[NB], obase[NB], cur[NB];
    __shared__ int2 staged[4096];
    int tid = threadIdx.x;
    if (tid < NB) cnts[tid] = 0;
    __syncthreads();
    int base = blockIdx.x * 4096;
    int dv[16], sv[16];
#pragma unroll
    for (int i = 0; i < 16; ++i) {
        int e = base + i * 256 + tid;
        if (e < NE) {
            dv[i] = ei[NE + e]; sv[i] = ei[e];
            atomicAdd(&cnts[dv[i] >> sh], 1);
        } else dv[i] = -1;
    }
    __syncthreads();
    if (tid < NB) scn[tid] = cnts[tid];
    __syncthreads();
    for (int off = 1; off < NB; off <<= 1) {
        int t = 0;
        if (tid < NB && tid >= off) t = scn[tid - off];
        __syncthreads();
        if (tid < NB) scn[tid] += t;
        __syncthreads();
    }
    if (tid < NB) {
        int ex = scn[tid] - cnts[tid];      // exclusive
        scn[tid] = ex;
        cur[tid] = ex;
        obase[tid] = (cnts[tid] > 0) ? atomicAdd(&a.gcnt[j][tid], cnts[tid]) : 0;
    }
    __syncthreads();
#pragma unroll
    for (int i = 0; i < 16; ++i) {
        if (dv[i] >= 0) {
            int b = dv[i] >> sh;
            int p = atomicAdd(&cur[b], 1);
            staged[p] = make_int2(dv[i], sv[i]);
        }
    }
    __syncthreads();
    int total = NE - base; if (total > 4096) total = 4096;
    int* pairs = a.pairs[j];
    int dmask = (1 << sh) - 1;
    for (int i = tid; i < total; i += 256) {
        int2 pr = staged[i];
        int b = pr.x >> sh;
        int gpos = obase[b] + (i - scn[b]);
        if (gpos < BCAP)                     // defensive (never hit when sized right)
            pairs[b * BCAP + gpos] = ((pr.x & dmask) << 17) | pr.y;
    }
}

// Phase A2: bucket bases = exclusive scan of counts; rowptr[Ndst] = NE.
struct BBArgs { int* gcnt[5]; int* bbase[5]; int* rowptr[5]; int ndst[5]; };
__global__ void k_bbase(BBArgs a)     // 5 blocks x 128 threads
{
    int j = blockIdx.x, tid = threadIdx.x;
    __shared__ int c[NB], s[NB];
    c[tid] = a.gcnt[j][tid];
    s[tid] = c[tid];
    __syncthreads();
    for (int off = 1; off < NB; off <<= 1) {
        int t = (tid >= off) ? s[tid - off] : 0;
        __syncthreads();
        s[tid] += t;
        __syncthreads();
    }
    a.bbase[j][tid] = s[tid] - c[tid];
    if (tid == 0) a.rowptr[j][a.ndst[j]] = NE;
}

// Phase B: per-bucket LDS counting sort over (1<<sh) local dsts ->
// sequential cols + rowptr writes.
struct BSArgs {
    const int* pairs[5]; const int* gcnt[5]; const int* bbase[5];
    int* cols[5]; int* rowptr[5]; int ndst[5];
};
__global__ void __launch_bounds__(256) k_bsort(BSArgs a)
{
    int j = blockIdx.y, b = blockIdx.x, tid = threadIdx.x;
    int sh = SHIFT_OF[j];
    int nloc = 1 << sh;
    int cnt = a.gcnt[j][b];
    if (cnt > BCAP) cnt = BCAP;
    int base = a.bbase[j][b];
    int d0 = b << sh;
    int ndst = a.ndst[j];
    __shared__ int cnts[1024], scn[1024], tsum[256];
    __shared__ int staged[BCAP];
    for (int i = tid; i < 1024; i += 256) cnts[i] = 0;
    __syncthreads();
    const int* pp = a.pairs[j] + b * BCAP;
    for (int i = tid; i < cnt; i += 256) atomicAdd(&cnts[pp[i] >> 17], 1);
    __syncthreads();
    int t0 = tid * 4;
    int l0 = cnts[t0], l1 = cnts[t0 + 1], l2 = cnts[t0 + 2], l3 = cnts[t0 + 3];
    int lsum = l0 + l1 + l2 + l3;
    tsum[tid] = lsum;
    __syncthreads();
    for (int off = 1; off < 256; off <<= 1) {
        int t = (tid >= off) ? tsum[tid - off] : 0;
        __syncthreads();
        tsum[tid] += t;
        __syncthreads();
    }
    int ex = tsum[tid] - lsum;
    scn[t0] = ex; scn[t0 + 1] = ex + l0;
    scn[t0 + 2] = ex + l0 + l1; scn[t0 + 3] = ex + l0 + l1 + l2;
    __syncthreads();
    for (int i = tid; i < 1024; i += 256) cnts[i] = scn[i];   // cursor
    __syncthreads();
    for (int i = tid; i < cnt; i += 256) {
        int v = pp[i];
        int p = atomicAdd(&cnts[v >> 17], 1);
        staged[p] = v & 0x1FFFF;
    }
    __syncthreads();
    int* cols = a.cols[j];
    for (int i = tid; i < cnt; i += 256) cols[base + i] = staged[i];
    int dlim = ndst - d0;
    if (dlim > nloc) dlim = nloc;
    for (int t = tid; t < dlim; t += 256) a.rowptr[j][d0 + t] = base + scn[t];
}

// ------------------ fused per-dst GAT gather + LN + ReLU -------------------
// w-dedup: lanes 0..31 compute w for (slot u=lane>>2, head=lane&3) once;
// channel-lanes read w via shfl.  (round-11 best-measured version)
__device__ __forceinline__ float gat_side(int n, int lane, int c, int hh, float hrow,
    const float* We, const int* __restrict__ rp, const int* __restrict__ cols,
    const __hip_bfloat16* __restrict__ hs, const float* __restrict__ als)
{
    float aldv = 0.f;
#pragma unroll
    for (int hp = 0; hp < 4; ++hp) {
        float v = hrow * We[c * 4 + hp];
        v += __shfl_xor(v, 32, 64);
        v += __shfl_xor(v, 16, 64);
        v += __shfl_xor(v, 8, 64);
        v += __shfl_xor(v, 4, 64);
        v += __shfl_xor(v, 2, 64);
        v += __shfl_xor(v, 1, 64);
        if (hh == hp) aldv = v;
    }
    float aldc = __shfl(aldv, (lane & 3) * 16, 64);
    int us = (lane >> 2) & 7;                 // this lane's w-slot
    float acc = 0.f, den = 0.f;
    int beg = rp[n], end = rp[n + 1];
    for (int e = beg; e < end; e += 8) {
        int idx[8];
#pragma unroll
        for (int u = 0; u < 8; ++u) {
            int ee = e + u;
            idx[u] = cols[(ee < end) ? ee : beg];
        }
        float alv = als[(size_t)idx[us] * 4 + (lane & 3)] + aldc;
        alv = (alv > 0.f) ? alv : 0.2f * alv;      // leaky_relu 0.2
        float wcomp = __expf(fminf(alv, 60.f));
        if (e + us >= end) wcomp = 0.f;
        float gv[8];
#pragma unroll
        for (int u = 0; u < 8; ++u) gv[u] = b2f(hs[(size_t)idx[u] * 64 + c]);
#pragma unroll
        for (int u = 0; u < 8; ++u) {
            float w = __shfl(wcomp, u * 4 + hh, 64);
            acc = fmaf(w, gv[u], acc);
            den += w;
        }
    }
    return acc / (den + 1e-16f);
}

struct DstArgs {
    __hip_bfloat16* h; int net; int last; int pad;
    const int* rp0; const int* cols0; const __hip_bfloat16* hs0; const float* als0;
    const float* Wd0; const float* ad0; const float* b0;
    const int* rp1; const int* cols1; const __hip_bfloat16* hs1; const float* als1;
    const float* Wd1; const float* ad1; const float* b1;
    const float* g; const float* bb;
    void* out; size_t obase; const int* flag;
};
struct DstAll { DstArgs a[3]; int blkoff[4]; };

__global__ void k_dst(DstAll all)
{
    int bid = blockIdx.x;
    int t = (bid >= all.blkoff[1]) + (bid >= all.blkoff[2]);
    const DstArgs& a = all.a[t];
    __shared__ float We0[256], We1[256];
    int tid = threadIdx.x;
    {
        int k = tid >> 2, h2 = tid & 3;
        float s0 = 0.f;
        for (int cc = 0; cc < 16; ++cc)
            s0 += a.Wd0[k * 64 + h2 * 16 + cc] * a.ad0[h2 * 16 + cc];
        We0[tid] = s0;
        if (a.net > 1) {
            float s1 = 0.f;
            for (int cc = 0; cc < 16; ++cc)
                s1 += a.Wd1[k * 64 + h2 * 16 + cc] * a.ad1[h2 * 16 + cc];
            We1[tid] = s1;
        }
    }
    __syncthreads();
    int wid = tid >> 6, lane = tid & 63, c = lane, hh = c >> 4;
    float b0c = a.b0[c];
    float b1c = (a.net > 1) ? a.b1[c] : 0.f;
    float gc = a.g[c], bbc = a.bb[c];
    int base = (bid - all.blkoff[t]) * 16;    // 16 nodes/block
    for (int r = 0; r < 4; ++r) {
        int n = base + r * 4 + wid;
        size_t i64 = (size_t)n * 64 + c;
        float hrow = b2f(a.h[i64]);
        float x = hrow + b0c + b1c;
        x += gat_side(n, lane, c, hh, hrow, We0, a.rp0, a.cols0, a.hs0, a.als0);
        if (a.net > 1)
            x += gat_side(n, lane, c, hh, hrow, We1, a.rp1, a.cols1, a.hs1, a.als1);
        float s = x;
#pragma unroll
        for (int off = 32; off >= 1; off >>= 1) s += __shfl_xor(s, off, 64);
        float mu = s * (1.f / 64.f);
        float dlt = x - mu;
        float v2 = dlt * dlt;
#pragma unroll
        for (int off = 32; off >= 1; off >>= 1) v2 += __shfl_xor(v2, off, 64);
        float y = dlt * rsqrtf(v2 * (1.f / 64.f) + 1e-5f) * gc + bbc;
        y = fmaxf(y, 0.f);
        if (!a.last) a.h[i64] = f2b(y);
        else {
            if (*a.flag) ((float*)a.out)[a.obase + i64] = y;
            else         ((__hip_bfloat16*)a.out)[a.obase + i64] = f2b(y);
        }
    }
}

extern "C" void kernel_launch(void* const* d_in, const int* in_sizes, int n_in,
                              void* d_out, int out_size, void* d_ws, size_t ws_size,
                              hipStream_t stream)
{
    (void)n_in; (void)out_size; (void)ws_size;
    char* ws = (char*)d_ws;
    int* flag = (int*)ws;
    float* params = (float*)(ws + 256);

    size_t off[17]; off[0] = 0;
    for (int i = 0; i < 16; ++i) off[i + 1] = off[i] + (size_t)in_sizes[i];

    const float* Wi = params + off[3]; const float* bi = params + off[4];
    const float* Wq = params + off[5]; const float* bq = params + off[6];
    const float* Wt = params + off[7]; const float* bt = params + off[8];
    const float* Wsrc = params + off[9];
    const float* Wdst = params + off[10];
    const float* asrc = params + off[11];
    const float* adst = params + off[12];
    const float* cbias = params + off[13];
    const float* lng = params + off[14];
    const float* lnb = params + off[15];

    __hip_bfloat16* h   = (__hip_bfloat16*)(ws + 7600000);
    __hip_bfloat16* h_i = h;
    __hip_bfloat16* h_q = h + (size_t)NI * 64;
    __hip_bfloat16* h_t = h + (size_t)(NI + NQ) * 64;
    __hip_bfloat16* hs_all = (__hip_bfloat16*)(ws + 39600000);
    float* als_all = (float*)(ws + 97200000);
    const size_t rowbase[5] = { 0, 100000, 200000, 300000, 400000 };

    const size_t RPS = 400032;
    const int Ndst_of[5] = { NI, NQ, NI, NT, NQ };
    int* rowptr[5]; int* cols[5]; int* pairs[5]; int* gcnt[5]; int* bbase[5];
    for (int j = 0; j < 5; ++j) {
        rowptr[j] = (int*)(ws + 104400000 + j * RPS);
        cols[j]   = (int*)(ws + 106400384 + (size_t)j * 2000000);
        pairs[j]  = (int*)(ws + 116400384 + (size_t)j * NB * BCAP * 4);
        gcnt[j]   = (int*)(ws + 132129024 + j * NB * 4);
        bbase[j]  = (int*)(ws + 132131584 + j * NB * 4);
    }

    // ---- dtype detect + widen PARAM tensors (3..15) only ----
    k_detect<<<1, 256, 0, stream>>>((const unsigned short*)d_in[0], flag);
    ConvArgs ca;
    for (int i = 0; i < 16; ++i) {
        ca.src[i] = d_in[i];
        ca.dst[i] = params + off[i];
        ca.n[i] = (i >= 3) ? in_sizes[i] : 0;
    }
    k_convert<<<dim3(160, 16), 256, 0, stream>>>(ca, flag);

    // ---- input projections ----
    k_inproj<<<(NI + 3) / 4, 256, 0, stream>>>(d_in[0], NI, 8, Wi, bi, h_i, flag);
    k_inproj<<<(NQ + 3) / 4, 256, 0, stream>>>(d_in[1], NQ, 6, Wq, bq, h_q, flag);
    k_inproj<<<(NT + 3) / 4, 256, 0, stream>>>(d_in[2], NT, 8, Wt, bt, h_t, flag);

    // ---- two-phase radix sort by dst (reused by both layers) ----
    hipMemsetAsync(ws + 132129024, 0, 5 * NB * 4, stream);   // gcnt
    BinArgs ba;
    BBArgs bb;
    BSArgs bs;
    for (int j = 0; j < 5; ++j) {
        ba.ei[j] = (const int*)d_in[16 + j];
        ba.pairs[j] = pairs[j];
        ba.gcnt[j] = gcnt[j];
        bb.gcnt[j] = gcnt[j]; bb.bbase[j] = bbase[j];
        bb.rowptr[j] = rowptr[j]; bb.ndst[j] = Ndst_of[j];
        bs.pairs[j] = pairs[j]; bs.gcnt[j] = gcnt[j]; bs.bbase[j] = bbase[j];
        bs.cols[j] = cols[j]; bs.rowptr[j] = rowptr[j]; bs.ndst[j] = Ndst_of[j];
    }
    k_bin<<<dim3((NE + 4095) / 4096, 5), 256, 0, stream>>>(ba);
    k_bbase<<<5, NB, 0, stream>>>(bb);
    k_bsort<<<dim3(NB, 5), 256, 0, stream>>>(bs);

    const __hip_bfloat16* hsrc_of[5] = { h_i, h_i, h_q, h_q, h_t };

    for (int l = 0; l < 2; ++l) {
        TfArgs ta;
        for (int j = 0; j < 5; ++j) {
            ta.hsrc[j] = hsrc_of[j];
            ta.W[j] = Wsrc + (size_t)(l * 5 + j) * 4096;
            ta.avec[j] = asrc + (l * 5 + j) * 64;
            ta.hs[j] = hs_all + rowbase[j] * 64;
            ta.als[j] = als_all + rowbase[j] * 4;
        }
        k_transform_all<<<450000 / 80, 256, 0, stream>>>(ta);

        int last = (l == 1);
        DstAll da;
        da.blkoff[0] = 0; da.blkoff[1] = NI / 16;
        da.blkoff[2] = NI / 16 + NQ / 16; da.blkoff[3] = NI / 16 + NQ / 16 + NT / 16;
        struct Spec { __hip_bfloat16* hd; int j0, j1, lnidx; size_t obase; };
        Spec sp[3] = {
            { h_i, 0, 2, 0, 0 },
            { h_q, 1, 4, 1, (size_t)NI * 64 },
            { h_t, 3, -1, 2, (size_t)(NI + NQ) * 64 },
        };
        for (int t = 0; t < 3; ++t) {
            DstArgs& dd = da.a[t];
            dd.h = sp[t].hd; dd.net = (sp[t].j1 >= 0) ? 2 : 1; dd.last = last; dd.pad = 0;
            int j0 = sp[t].j0;
            dd.rp0 = rowptr[j0]; dd.cols0 = cols[j0];
            dd.hs0 = hs_all + rowbase[j0] * 64; dd.als0 = als_all + rowbase[j0] * 4;
            dd.Wd0 = Wdst + (size_t)(l * 5 + j0) * 4096;
            dd.ad0 = adst + (l * 5 + j0) * 64;
            dd.b0 = cbias + (size_t)(l * 5 + j0) * 64;
            int jj = (sp[t].j1 >= 0) ? sp[t].j1 : j0;
            dd.rp1 = rowptr[jj]; dd.cols1 = cols[jj];
            dd.hs1 = hs_all + rowbase[jj] * 64; dd.als1 = als_all + rowbase[jj] * 4;
            dd.Wd1 = Wdst + (size_t)(l * 5 + jj) * 4096;
            dd.ad1 = adst + (l * 5 + jj) * 64;
            dd.b1 = cbias + (size_t)(l * 5 + jj) * 64;
            dd.g = lng + (size_t)(l * 3 + sp[t].lnidx) * 64;
            dd.bb = lnb + (size_t)(l * 3 + sp[t].lnidx) * 64;
            dd.out = d_out; dd.obase = sp[t].obase; dd.flag = flag;
        }
        k_dst<<<da.blkoff[3], 256, 0, stream>>>(da);
    }
}